// Round 1
// baseline (238.640 us; speedup 1.0000x reference)
//
#include <hip/hip_runtime.h>

#define B_    4
#define CIN_  64
#define COUT_ 64
#define N_    16384
#define K_    8

#define EDGES_PER_B (K_ * N_)            // 131072
#define TOT_EDGES   (B_ * EDGES_PER_B)   // 524288

// ===========================================================================
// FAST PATH (needs ~67 MB workspace): scatter -> gather via counting sort.
// ===========================================================================

// --- 1. histogram of incoming-edge counts per target point j ---------------
__global__ __launch_bounds__(256) void fc_hist(
    const int* __restrict__ nbh,      // [B, K, N] flat
    int*       __restrict__ counts)   // [B, N]
{
    const int gid = blockIdx.x * 256 + threadIdx.x;     // < TOT_EDGES
    const int b   = gid / EDGES_PER_B;
    const int j   = nbh[gid];
    atomicAdd(&counts[b * N_ + j], 1);
}

// --- 2. per-batch exclusive scan of counts -> offsets (+ cursor copy) ------
__global__ __launch_bounds__(256) void fc_scan(
    const int* __restrict__ counts,
    int*       __restrict__ offsets,
    int*       __restrict__ cursor)
{
    __shared__ int s[256];
    const int b = blockIdx.x;
    const int t = threadIdx.x;
    const int base = b * N_ + t * 64;   // each thread owns 64 consecutive bins

    int sum = 0;
    #pragma unroll
    for (int e = 0; e < 64; ++e) sum += counts[base + e];
    s[t] = sum;
    __syncthreads();

    // Hillis-Steele inclusive scan over 256 thread-chunk totals.
    for (int d = 1; d < 256; d <<= 1) {
        const int v = (t >= d) ? s[t - d] : 0;
        __syncthreads();
        s[t] += v;
        __syncthreads();
    }

    int off = s[t] - sum;               // exclusive base for this chunk
    #pragma unroll
    for (int e = 0; e < 64; ++e) {
        const int c = counts[base + e];
        offsets[base + e] = off;
        cursor[base + e]  = off;
        off += c;
    }
}

// --- 3. fill edge list sorted by target j ----------------------------------
__global__ __launch_bounds__(256) void fc_fill(
    const int* __restrict__ nbh,
    int*       __restrict__ cursor,
    int*       __restrict__ edges)    // [B, K*N] source-point id per edge
{
    const int gid = blockIdx.x * 256 + threadIdx.x;     // < TOT_EDGES
    const int b   = gid / EDGES_PER_B;
    const int n   = gid % N_;                            // layout [B,K,N]
    const int j   = nbh[gid];
    const int slot = atomicAdd(&cursor[b * N_ + j], 1);
    edges[b * EDGES_PER_B + slot] = n;
}

// --- 4. phase 1: per source point n store (ft0,ft1,ft2,h), h = fb - pos_n.ft
// Same GEMM structure as the verified atomic kernel; scatter replaced by one
// coalesced float4 store per (n,o).
__global__ __launch_bounds__(256) void fc_ftfb(
    const float* __restrict__ feat,    // [B, CIN, N]
    const float* __restrict__ theta,   // [3, CIN, COUT]
    const float* __restrict__ wbias,   // [CIN, COUT]
    const float* __restrict__ pos,     // [B, 3, N]
    float4*      __restrict__ ftfb)    // [B, N, COUT] float4 per (n,o)
{
    __shared__ float4 Wl[CIN_ * COUT_];   // 64 KiB: (theta0,theta1,theta2,wb)
    __shared__ float  Fl[CIN_ * 64];      // 16 KiB feature tile [i][nn]

    const int tid  = threadIdx.x;
    const int lane = tid & 63;            // o
    const int w    = tid >> 6;            // wave id 0..3

    const int blocks_per_b = N_ / 128;    // 128
    const int b     = blockIdx.x / blocks_per_b;
    const int nbase = (blockIdx.x % blocks_per_b) * 128;

    for (int e = tid; e < CIN_ * COUT_; e += 256) {
        const int i = e >> 6, o = e & 63;
        float4 wv;
        wv.x = theta[0 * CIN_ * COUT_ + i * COUT_ + o];
        wv.y = theta[1 * CIN_ * COUT_ + i * COUT_ + o];
        wv.z = theta[2 * CIN_ * COUT_ + i * COUT_ + o];
        wv.w = wbias[i * COUT_ + o];
        Wl[e] = wv;
    }

    const float* featb = feat + (size_t)b * CIN_ * N_;
    const float* posb  = pos  + (size_t)b * 3 * N_;

    for (int t = 0; t < 2; ++t) {
        const int n0 = nbase + t * 64;

        __syncthreads();
        for (int r = 0; r < 16; ++r) {
            const int i = r * 4 + w;
            Fl[i * 64 + lane] = featb[(size_t)i * N_ + n0 + lane];
        }
        __syncthreads();

        for (int g = 0; g < 4; ++g) {
            const int nn = w * 16 + g * 4;
            float4 acc[4];
            #pragma unroll
            for (int j = 0; j < 4; ++j) acc[j] = make_float4(0.f, 0.f, 0.f, 0.f);

            #pragma unroll 8
            for (int i = 0; i < CIN_; ++i) {
                const float4 wv = Wl[i * 64 + lane];
                const float f0 = Fl[i * 64 + nn + 0];
                const float f1 = Fl[i * 64 + nn + 1];
                const float f2 = Fl[i * 64 + nn + 2];
                const float f3 = Fl[i * 64 + nn + 3];
                acc[0].x = fmaf(wv.x, f0, acc[0].x);
                acc[0].y = fmaf(wv.y, f0, acc[0].y);
                acc[0].z = fmaf(wv.z, f0, acc[0].z);
                acc[0].w = fmaf(wv.w, f0, acc[0].w);
                acc[1].x = fmaf(wv.x, f1, acc[1].x);
                acc[1].y = fmaf(wv.y, f1, acc[1].y);
                acc[1].z = fmaf(wv.z, f1, acc[1].z);
                acc[1].w = fmaf(wv.w, f1, acc[1].w);
                acc[2].x = fmaf(wv.x, f2, acc[2].x);
                acc[2].y = fmaf(wv.y, f2, acc[2].y);
                acc[2].z = fmaf(wv.z, f2, acc[2].z);
                acc[2].w = fmaf(wv.w, f2, acc[2].w);
                acc[3].x = fmaf(wv.x, f3, acc[3].x);
                acc[3].y = fmaf(wv.y, f3, acc[3].y);
                acc[3].z = fmaf(wv.z, f3, acc[3].z);
                acc[3].w = fmaf(wv.w, f3, acc[3].w);
            }

            #pragma unroll
            for (int j = 0; j < 4; ++j) {
                const int n = n0 + nn + j;
                const float px = posb[0 * N_ + n];
                const float py = posb[1 * N_ + n];
                const float pz = posb[2 * N_ + n];
                float4 a = acc[j];
                // h = fb - pos_n . ft
                a.w = fmaf(-px, a.x, fmaf(-py, a.y, fmaf(-pz, a.z, a.w)));
                ftfb[(((size_t)b * N_ + n) << 6) + lane] = a;   // 1KB/wave, coalesced
            }
        }
    }
}

// --- 5. gather: out[b][o][j] = bias[o] + sum_edges( pos_j . ft(n) + h(n) ) --
__global__ __launch_bounds__(256) void fc_gather(
    const float4* __restrict__ ftfb,
    const int*    __restrict__ edges,
    const int*    __restrict__ offsets,
    const int*    __restrict__ counts,
    const float*  __restrict__ pos,
    const float*  __restrict__ bias,
    float*        __restrict__ out)    // [B, COUT, N]
{
    __shared__ float T[64][65];
    const int tid  = threadIdx.x;
    const int lane = tid & 63;            // o
    const int w    = tid >> 6;

    const int tiles_per_b = N_ / 64;      // 256
    const int b  = blockIdx.x / tiles_per_b;
    const int n0 = (blockIdx.x % tiles_per_b) * 64;

    const float4* fb4  = ftfb + ((size_t)b * N_ << 6);
    const int*    eb   = edges + b * EDGES_PER_B;
    const float*  posb = pos + (size_t)b * 3 * N_;

    for (int g = 0; g < 16; ++g) {
        const int jj = w * 16 + g;
        const int j  = n0 + jj;
        const int base = offsets[b * N_ + j];
        const int cnt  = counts[b * N_ + j];
        const float px = posb[0 * N_ + j];
        const float py = posb[1 * N_ + j];
        const float pz = posb[2 * N_ + j];

        float acc = 0.f;
        int e = 0;
        for (; e + 4 <= cnt; e += 4) {      // 4 independent loads in flight
            const int m0 = eb[base + e + 0];
            const int m1 = eb[base + e + 1];
            const int m2 = eb[base + e + 2];
            const int m3 = eb[base + e + 3];
            const float4 v0 = fb4[(m0 << 6) + lane];
            const float4 v1 = fb4[(m1 << 6) + lane];
            const float4 v2 = fb4[(m2 << 6) + lane];
            const float4 v3 = fb4[(m3 << 6) + lane];
            acc += fmaf(px, v0.x, fmaf(py, v0.y, fmaf(pz, v0.z, v0.w)));
            acc += fmaf(px, v1.x, fmaf(py, v1.y, fmaf(pz, v1.z, v1.w)));
            acc += fmaf(px, v2.x, fmaf(py, v2.y, fmaf(pz, v2.z, v2.w)));
            acc += fmaf(px, v3.x, fmaf(py, v3.y, fmaf(pz, v3.z, v3.w)));
        }
        for (; e < cnt; ++e) {
            const int m = eb[base + e];
            const float4 v = fb4[(m << 6) + lane];
            acc += fmaf(px, v.x, fmaf(py, v.y, fmaf(pz, v.z, v.w)));
        }
        T[jj][lane] = acc;
    }
    __syncthreads();

    float* outb = out + (size_t)b * COUT_ * N_;
    for (int r = 0; r < 16; ++r) {
        const int o = r * 4 + w;
        outb[(size_t)o * N_ + n0 + lane] = T[lane][o] + bias[o];  // coalesced
    }
}

// ===========================================================================
// FALLBACK PATH (16 MB workspace): previous verified atomic-scatter version.
// ===========================================================================
__global__ __launch_bounds__(256) void flexconv_main(
    const float* __restrict__ feat,
    const float* __restrict__ theta,
    const float* __restrict__ wbias,
    const int*   __restrict__ nbh,
    const float* __restrict__ pos,
    float*       __restrict__ ws)
{
    __shared__ float4 Wl[CIN_ * COUT_];
    __shared__ float  Fl[CIN_ * 64];

    const int tid  = threadIdx.x;
    const int lane = tid & 63;
    const int w    = tid >> 6;

    const int blocks_per_b = N_ / 128;
    const int b     = blockIdx.x / blocks_per_b;
    const int nbase = (blockIdx.x % blocks_per_b) * 128;

    for (int e = tid; e < CIN_ * COUT_; e += 256) {
        const int i = e >> 6, o = e & 63;
        float4 wv;
        wv.x = theta[0 * CIN_ * COUT_ + i * COUT_ + o];
        wv.y = theta[1 * CIN_ * COUT_ + i * COUT_ + o];
        wv.z = theta[2 * CIN_ * COUT_ + i * COUT_ + o];
        wv.w = wbias[i * COUT_ + o];
        Wl[e] = wv;
    }

    const float* featb = feat + (size_t)b * CIN_ * N_;
    const float* posb  = pos  + (size_t)b * 3 * N_;
    const int*   nbhb  = nbh  + (size_t)b * K_ * N_;
    float*       wsb   = ws   + (size_t)b * N_ * COUT_;

    for (int t = 0; t < 2; ++t) {
        const int n0 = nbase + t * 64;

        __syncthreads();
        for (int r = 0; r < 16; ++r) {
            const int i = r * 4 + w;
            Fl[i * 64 + lane] = featb[(size_t)i * N_ + n0 + lane];
        }
        __syncthreads();

        for (int g = 0; g < 4; ++g) {
            const int nn = w * 16 + g * 4;
            float4 acc[4];
            #pragma unroll
            for (int j = 0; j < 4; ++j) acc[j] = make_float4(0.f, 0.f, 0.f, 0.f);

            #pragma unroll 8
            for (int i = 0; i < CIN_; ++i) {
                const float4 wv = Wl[i * 64 + lane];
                const float f0 = Fl[i * 64 + nn + 0];
                const float f1 = Fl[i * 64 + nn + 1];
                const float f2 = Fl[i * 64 + nn + 2];
                const float f3 = Fl[i * 64 + nn + 3];
                acc[0].x = fmaf(wv.x, f0, acc[0].x);
                acc[0].y = fmaf(wv.y, f0, acc[0].y);
                acc[0].z = fmaf(wv.z, f0, acc[0].z);
                acc[0].w = fmaf(wv.w, f0, acc[0].w);
                acc[1].x = fmaf(wv.x, f1, acc[1].x);
                acc[1].y = fmaf(wv.y, f1, acc[1].y);
                acc[1].z = fmaf(wv.z, f1, acc[1].z);
                acc[1].w = fmaf(wv.w, f1, acc[1].w);
                acc[2].x = fmaf(wv.x, f2, acc[2].x);
                acc[2].y = fmaf(wv.y, f2, acc[2].y);
                acc[2].z = fmaf(wv.z, f2, acc[2].z);
                acc[2].w = fmaf(wv.w, f2, acc[2].w);
                acc[3].x = fmaf(wv.x, f3, acc[3].x);
                acc[3].y = fmaf(wv.y, f3, acc[3].y);
                acc[3].z = fmaf(wv.z, f3, acc[3].z);
                acc[3].w = fmaf(wv.w, f3, acc[3].w);
            }

            #pragma unroll
            for (int j = 0; j < 4; ++j) {
                const int n = n0 + nn + j;
                const float px = posb[0 * N_ + n];
                const float py = posb[1 * N_ + n];
                const float pz = posb[2 * N_ + n];
                const float4 a = acc[j];
                #pragma unroll
                for (int k = 0; k < K_; ++k) {
                    const int idx = nbhb[k * N_ + n];
                    const float dx = posb[0 * N_ + idx] - px;
                    const float dy = posb[1 * N_ + idx] - py;
                    const float dz = posb[2 * N_ + idx] - pz;
                    const float c  = fmaf(dx, a.x, fmaf(dy, a.y, fmaf(dz, a.z, a.w)));
                    atomicAdd(&wsb[(size_t)idx * COUT_ + lane], c);
                }
            }
        }
    }
}

__global__ __launch_bounds__(256) void flexconv_finish(
    const float* __restrict__ ws,
    const float* __restrict__ bias,
    float*       __restrict__ out)
{
    __shared__ float T[64][65];
    const int tid  = threadIdx.x;
    const int lane = tid & 63;
    const int w    = tid >> 6;

    const int tiles_per_b = N_ / 64;
    const int b  = blockIdx.x / tiles_per_b;
    const int n0 = (blockIdx.x % tiles_per_b) * 64;

    const float* wsb = ws + (size_t)b * N_ * COUT_;
    for (int r = 0; r < 16; ++r) {
        const int nn = r * 4 + w;
        T[nn][lane] = wsb[(size_t)(n0 + nn) * COUT_ + lane];
    }
    __syncthreads();

    float* outb = out + (size_t)b * COUT_ * N_;
    for (int r = 0; r < 16; ++r) {
        const int o = r * 4 + w;
        outb[(size_t)o * N_ + n0 + lane] = T[lane][o] + bias[o];
    }
}

// ===========================================================================
extern "C" void kernel_launch(void* const* d_in, const int* in_sizes, int n_in,
                              void* d_out, int out_size, void* d_ws, size_t ws_size,
                              hipStream_t stream) {
    const float* features = (const float*)d_in[0];
    const float* theta    = (const float*)d_in[1];
    const float* wbias    = (const float*)d_in[2];
    const int*   nbh      = (const int*)  d_in[3];
    const float* pos      = (const float*)d_in[4];
    const float* bias     = (const float*)d_in[5];
    float* out = (float*)d_out;

    // Workspace layout for the fast path.
    const size_t ftfb_bytes    = (size_t)B_ * N_ * COUT_ * sizeof(float4); // 64 MiB
    const size_t counts_bytes  = (size_t)B_ * N_ * sizeof(int);            // 256 KiB
    const size_t edges_bytes   = (size_t)TOT_EDGES * sizeof(int);          // 2 MiB

    size_t off = 0;
    float4* ftfb    = (float4*)((char*)d_ws + off); off += ftfb_bytes;
    int*    counts  = (int*)   ((char*)d_ws + off); off += counts_bytes;
    int*    offsets = (int*)   ((char*)d_ws + off); off += counts_bytes;
    int*    cursor  = (int*)   ((char*)d_ws + off); off += counts_bytes;
    int*    edges   = (int*)   ((char*)d_ws + off); off += edges_bytes;
    const size_t need = off;

    if (ws_size >= need) {
        // -------- fast path: counting-sort gather, no float atomics --------
        hipMemsetAsync(counts, 0, counts_bytes, stream);
        fc_hist<<<TOT_EDGES / 256, 256, 0, stream>>>(nbh, counts);
        fc_scan<<<B_, 256, 0, stream>>>(counts, offsets, cursor);
        fc_fill<<<TOT_EDGES / 256, 256, 0, stream>>>(nbh, cursor, edges);
        fc_ftfb<<<B_ * (N_ / 128), 256, 0, stream>>>(features, theta, wbias, pos, ftfb);
        fc_gather<<<B_ * (N_ / 64), 256, 0, stream>>>(ftfb, edges, offsets, counts,
                                                      pos, bias, out);
    } else {
        // -------- fallback: previous verified atomic-scatter version -------
        float* ws = (float*)d_ws;
        const size_t ws_bytes = (size_t)B_ * N_ * COUT_ * sizeof(float);   // 16 MiB
        hipMemsetAsync(ws, 0, ws_bytes, stream);
        flexconv_main<<<B_ * (N_ / 128), 256, 0, stream>>>(features, theta, wbias,
                                                           nbh, pos, ws);
        flexconv_finish<<<B_ * (N_ / 64), 256, 0, stream>>>(ws, bias, out);
    }
}

// Round 2
// 204.448 us; speedup vs baseline: 1.1672x; 1.1672x over previous
//
#include <hip/hip_runtime.h>

#define B_    4
#define CIN_  64
#define COUT_ 64
#define N_    16384
#define K_    8

#define EDGES_PER_B (K_ * N_)            // 131072
#define TOT_EDGES   (B_ * EDGES_PER_B)   // 524288

// ===========================================================================
// Shared prep kernels (counting sort of edges by target j)
// ===========================================================================

// --- histogram of incoming-edge counts per target point j ------------------
__global__ __launch_bounds__(256) void fc_hist(
    const int* __restrict__ nbh,      // [B, K, N] flat
    int*       __restrict__ counts)   // [B, N]
{
    const int gid = blockIdx.x * 256 + threadIdx.x;     // < TOT_EDGES
    const int b   = gid / EDGES_PER_B;
    const int j   = nbh[gid];
    atomicAdd(&counts[b * N_ + j], 1);
}

// --- per-batch exclusive scan of counts -> offsets (+ cursor copy) ---------
__global__ __launch_bounds__(256) void fc_scan(
    const int* __restrict__ counts,
    int*       __restrict__ offsets,
    int*       __restrict__ cursor)
{
    __shared__ int s[256];
    const int b = blockIdx.x;
    const int t = threadIdx.x;
    const int base = b * N_ + t * 64;   // each thread owns 64 consecutive bins

    int sum = 0;
    #pragma unroll
    for (int e = 0; e < 64; ++e) sum += counts[base + e];
    s[t] = sum;
    __syncthreads();

    for (int d = 1; d < 256; d <<= 1) {
        const int v = (t >= d) ? s[t - d] : 0;
        __syncthreads();
        s[t] += v;
        __syncthreads();
    }

    int off = s[t] - sum;               // exclusive base for this chunk
    #pragma unroll
    for (int e = 0; e < 64; ++e) {
        const int c = counts[base + e];
        offsets[base + e] = off;
        cursor[base + e]  = off;
        off += c;
    }
}

// ===========================================================================
// PATH A (~131 MiB ws): per-edge contribs written target-sorted, read once.
// ===========================================================================

// --- assign each edge its slot in the target-sorted order ------------------
__global__ __launch_bounds__(256) void fc_fill_slot(
    const int* __restrict__ nbh,
    int*       __restrict__ cursor,
    int*       __restrict__ slotmap)  // [B, K*N] slot within batch
{
    const int gid = blockIdx.x * 256 + threadIdx.x;     // < TOT_EDGES
    const int b   = gid / EDGES_PER_B;
    const int j   = nbh[gid];
    slotmap[gid] = atomicAdd(&cursor[b * N_ + j], 1);
}

// --- phase 1: GEMM for ft/h per source point, then per-edge contribution
//     c[o] = pos_j . ft + h, written to the target-sorted slot.
__global__ __launch_bounds__(256) void fc_contrib(
    const float* __restrict__ feat,    // [B, CIN, N]
    const float* __restrict__ theta,   // [3, CIN, COUT]
    const float* __restrict__ wbias,   // [CIN, COUT]
    const int*   __restrict__ nbh,     // [B, K, N]
    const int*   __restrict__ slotmap, // [B, K*N]
    const float* __restrict__ pos,     // [B, 3, N]
    float*       __restrict__ contrib) // [B, K*N, COUT]
{
    __shared__ float4 Wl[CIN_ * COUT_];   // 64 KiB: (theta0,theta1,theta2,wb)
    __shared__ float  Fl[CIN_ * 64];      // 16 KiB feature tile [i][nn]

    const int tid  = threadIdx.x;
    const int lane = tid & 63;            // o
    const int w    = tid >> 6;            // wave id 0..3

    const int blocks_per_b = N_ / 128;    // 128
    const int b     = blockIdx.x / blocks_per_b;
    const int nbase = (blockIdx.x % blocks_per_b) * 128;

    for (int e = tid; e < CIN_ * COUT_; e += 256) {
        const int i = e >> 6, o = e & 63;
        float4 wv;
        wv.x = theta[0 * CIN_ * COUT_ + i * COUT_ + o];
        wv.y = theta[1 * CIN_ * COUT_ + i * COUT_ + o];
        wv.z = theta[2 * CIN_ * COUT_ + i * COUT_ + o];
        wv.w = wbias[i * COUT_ + o];
        Wl[e] = wv;
    }

    const float* featb = feat + (size_t)b * CIN_ * N_;
    const float* posb  = pos  + (size_t)b * 3 * N_;
    const int*   nbhb  = nbh  + (size_t)b * K_ * N_;
    const int*   smb   = slotmap + (size_t)b * EDGES_PER_B;
    float*       cb    = contrib + ((size_t)b * EDGES_PER_B << 6);

    for (int t = 0; t < 2; ++t) {
        const int n0 = nbase + t * 64;

        __syncthreads();
        for (int r = 0; r < 16; ++r) {
            const int i = r * 4 + w;
            Fl[i * 64 + lane] = featb[(size_t)i * N_ + n0 + lane];
        }
        __syncthreads();

        for (int g = 0; g < 4; ++g) {
            const int nn = w * 16 + g * 4;
            float4 acc[4];
            #pragma unroll
            for (int j = 0; j < 4; ++j) acc[j] = make_float4(0.f, 0.f, 0.f, 0.f);

            #pragma unroll 8
            for (int i = 0; i < CIN_; ++i) {
                const float4 wv = Wl[i * 64 + lane];
                const float f0 = Fl[i * 64 + nn + 0];
                const float f1 = Fl[i * 64 + nn + 1];
                const float f2 = Fl[i * 64 + nn + 2];
                const float f3 = Fl[i * 64 + nn + 3];
                acc[0].x = fmaf(wv.x, f0, acc[0].x);
                acc[0].y = fmaf(wv.y, f0, acc[0].y);
                acc[0].z = fmaf(wv.z, f0, acc[0].z);
                acc[0].w = fmaf(wv.w, f0, acc[0].w);
                acc[1].x = fmaf(wv.x, f1, acc[1].x);
                acc[1].y = fmaf(wv.y, f1, acc[1].y);
                acc[1].z = fmaf(wv.z, f1, acc[1].z);
                acc[1].w = fmaf(wv.w, f1, acc[1].w);
                acc[2].x = fmaf(wv.x, f2, acc[2].x);
                acc[2].y = fmaf(wv.y, f2, acc[2].y);
                acc[2].z = fmaf(wv.z, f2, acc[2].z);
                acc[2].w = fmaf(wv.w, f2, acc[2].w);
                acc[3].x = fmaf(wv.x, f3, acc[3].x);
                acc[3].y = fmaf(wv.y, f3, acc[3].y);
                acc[3].z = fmaf(wv.z, f3, acc[3].z);
                acc[3].w = fmaf(wv.w, f3, acc[3].w);
            }

            #pragma unroll
            for (int j = 0; j < 4; ++j) {
                const int n = n0 + nn + j;
                const float px = posb[0 * N_ + n];
                const float py = posb[1 * N_ + n];
                const float pz = posb[2 * N_ + n];
                float4 a = acc[j];
                // h = fb - pos_n . ft
                a.w = fmaf(-px, a.x, fmaf(-py, a.y, fmaf(-pz, a.z, a.w)));
                // per-edge contribution, written into target-sorted slot
                #pragma unroll
                for (int k = 0; k < K_; ++k) {
                    const int jt   = nbhb[k * N_ + n];      // broadcast
                    const int slot = smb[k * N_ + n];       // broadcast
                    const float qx = posb[0 * N_ + jt];
                    const float qy = posb[1 * N_ + jt];
                    const float qz = posb[2 * N_ + jt];
                    const float c  = fmaf(qx, a.x, fmaf(qy, a.y, fmaf(qz, a.z, a.w)));
                    cb[((size_t)slot << 6) + lane] = c;     // 256 B / wave
                }
            }
        }
    }
}

// --- gather: per target j, contiguous read of its cnt*256B contrib range ---
__global__ __launch_bounds__(512) void fc_gather3(
    const float* __restrict__ contrib,
    const int*   __restrict__ offsets,
    const int*   __restrict__ counts,
    const float* __restrict__ bias,
    float*       __restrict__ out)     // [B, COUT, N]
{
    __shared__ float T[64][65];
    const int tid  = threadIdx.x;
    const int lane = tid & 63;            // o
    const int w    = tid >> 6;            // wave id 0..7

    const int tiles_per_b = N_ / 64;      // 256
    const int b  = blockIdx.x / tiles_per_b;
    const int n0 = (blockIdx.x % tiles_per_b) * 64;

    const float* cb = contrib + ((size_t)b * EDGES_PER_B << 6);

    for (int g = 0; g < 8; ++g) {
        const int jj = w * 8 + g;
        const int j  = n0 + jj;
        const int base = offsets[b * N_ + j];
        const int cnt  = counts[b * N_ + j];

        const float* p = cb + ((size_t)base << 6) + lane;
        float acc = 0.f;
        int e = 0;
        for (; e + 4 <= cnt; e += 4) {
            const float v0 = p[0];
            const float v1 = p[64];
            const float v2 = p[128];
            const float v3 = p[192];
            acc += (v0 + v1) + (v2 + v3);
            p += 256;
        }
        for (; e < cnt; ++e) { acc += *p; p += 64; }
        T[jj][lane] = acc;
    }
    __syncthreads();

    float* outb = out + (size_t)b * COUT_ * N_;
    for (int r = 0; r < 8; ++r) {
        const int o = r * 8 + w;
        outb[(size_t)o * N_ + n0 + lane] = T[lane][o] + bias[o];  // coalesced
    }
}

// ===========================================================================
// PATH B (~67 MiB ws): round-1 pipeline (ftfb + edge-list gather).
// ===========================================================================

__global__ __launch_bounds__(256) void fc_fill(
    const int* __restrict__ nbh,
    int*       __restrict__ cursor,
    int*       __restrict__ edges)    // [B, K*N] source-point id per edge
{
    const int gid = blockIdx.x * 256 + threadIdx.x;     // < TOT_EDGES
    const int b   = gid / EDGES_PER_B;
    const int n   = gid % N_;                            // layout [B,K,N]
    const int j   = nbh[gid];
    const int slot = atomicAdd(&cursor[b * N_ + j], 1);
    edges[b * EDGES_PER_B + slot] = n;
}

__global__ __launch_bounds__(256) void fc_ftfb(
    const float* __restrict__ feat,
    const float* __restrict__ theta,
    const float* __restrict__ wbias,
    const float* __restrict__ pos,
    float4*      __restrict__ ftfb)    // [B, N, COUT] float4 per (n,o)
{
    __shared__ float4 Wl[CIN_ * COUT_];
    __shared__ float  Fl[CIN_ * 64];

    const int tid  = threadIdx.x;
    const int lane = tid & 63;
    const int w    = tid >> 6;

    const int blocks_per_b = N_ / 128;
    const int b     = blockIdx.x / blocks_per_b;
    const int nbase = (blockIdx.x % blocks_per_b) * 128;

    for (int e = tid; e < CIN_ * COUT_; e += 256) {
        const int i = e >> 6, o = e & 63;
        float4 wv;
        wv.x = theta[0 * CIN_ * COUT_ + i * COUT_ + o];
        wv.y = theta[1 * CIN_ * COUT_ + i * COUT_ + o];
        wv.z = theta[2 * CIN_ * COUT_ + i * COUT_ + o];
        wv.w = wbias[i * COUT_ + o];
        Wl[e] = wv;
    }

    const float* featb = feat + (size_t)b * CIN_ * N_;
    const float* posb  = pos  + (size_t)b * 3 * N_;

    for (int t = 0; t < 2; ++t) {
        const int n0 = nbase + t * 64;

        __syncthreads();
        for (int r = 0; r < 16; ++r) {
            const int i = r * 4 + w;
            Fl[i * 64 + lane] = featb[(size_t)i * N_ + n0 + lane];
        }
        __syncthreads();

        for (int g = 0; g < 4; ++g) {
            const int nn = w * 16 + g * 4;
            float4 acc[4];
            #pragma unroll
            for (int j = 0; j < 4; ++j) acc[j] = make_float4(0.f, 0.f, 0.f, 0.f);

            #pragma unroll 8
            for (int i = 0; i < CIN_; ++i) {
                const float4 wv = Wl[i * 64 + lane];
                const float f0 = Fl[i * 64 + nn + 0];
                const float f1 = Fl[i * 64 + nn + 1];
                const float f2 = Fl[i * 64 + nn + 2];
                const float f3 = Fl[i * 64 + nn + 3];
                acc[0].x = fmaf(wv.x, f0, acc[0].x);
                acc[0].y = fmaf(wv.y, f0, acc[0].y);
                acc[0].z = fmaf(wv.z, f0, acc[0].z);
                acc[0].w = fmaf(wv.w, f0, acc[0].w);
                acc[1].x = fmaf(wv.x, f1, acc[1].x);
                acc[1].y = fmaf(wv.y, f1, acc[1].y);
                acc[1].z = fmaf(wv.z, f1, acc[1].z);
                acc[1].w = fmaf(wv.w, f1, acc[1].w);
                acc[2].x = fmaf(wv.x, f2, acc[2].x);
                acc[2].y = fmaf(wv.y, f2, acc[2].y);
                acc[2].z = fmaf(wv.z, f2, acc[2].z);
                acc[2].w = fmaf(wv.w, f2, acc[2].w);
                acc[3].x = fmaf(wv.x, f3, acc[3].x);
                acc[3].y = fmaf(wv.y, f3, acc[3].y);
                acc[3].z = fmaf(wv.z, f3, acc[3].z);
                acc[3].w = fmaf(wv.w, f3, acc[3].w);
            }

            #pragma unroll
            for (int j = 0; j < 4; ++j) {
                const int n = n0 + nn + j;
                const float px = posb[0 * N_ + n];
                const float py = posb[1 * N_ + n];
                const float pz = posb[2 * N_ + n];
                float4 a = acc[j];
                a.w = fmaf(-px, a.x, fmaf(-py, a.y, fmaf(-pz, a.z, a.w)));
                ftfb[(((size_t)b * N_ + n) << 6) + lane] = a;
            }
        }
    }
}

__global__ __launch_bounds__(256) void fc_gather(
    const float4* __restrict__ ftfb,
    const int*    __restrict__ edges,
    const int*    __restrict__ offsets,
    const int*    __restrict__ counts,
    const float*  __restrict__ pos,
    const float*  __restrict__ bias,
    float*        __restrict__ out)
{
    __shared__ float T[64][65];
    const int tid  = threadIdx.x;
    const int lane = tid & 63;
    const int w    = tid >> 6;

    const int tiles_per_b = N_ / 64;
    const int b  = blockIdx.x / tiles_per_b;
    const int n0 = (blockIdx.x % tiles_per_b) * 64;

    const float4* fb4  = ftfb + ((size_t)b * N_ << 6);
    const int*    eb   = edges + b * EDGES_PER_B;
    const float*  posb = pos + (size_t)b * 3 * N_;

    for (int g = 0; g < 16; ++g) {
        const int jj = w * 16 + g;
        const int j  = n0 + jj;
        const int base = offsets[b * N_ + j];
        const int cnt  = counts[b * N_ + j];
        const float px = posb[0 * N_ + j];
        const float py = posb[1 * N_ + j];
        const float pz = posb[2 * N_ + j];

        float acc = 0.f;
        int e = 0;
        for (; e + 4 <= cnt; e += 4) {
            const int m0 = eb[base + e + 0];
            const int m1 = eb[base + e + 1];
            const int m2 = eb[base + e + 2];
            const int m3 = eb[base + e + 3];
            const float4 v0 = fb4[(m0 << 6) + lane];
            const float4 v1 = fb4[(m1 << 6) + lane];
            const float4 v2 = fb4[(m2 << 6) + lane];
            const float4 v3 = fb4[(m3 << 6) + lane];
            acc += fmaf(px, v0.x, fmaf(py, v0.y, fmaf(pz, v0.z, v0.w)));
            acc += fmaf(px, v1.x, fmaf(py, v1.y, fmaf(pz, v1.z, v1.w)));
            acc += fmaf(px, v2.x, fmaf(py, v2.y, fmaf(pz, v2.z, v2.w)));
            acc += fmaf(px, v3.x, fmaf(py, v3.y, fmaf(pz, v3.z, v3.w)));
        }
        for (; e < cnt; ++e) {
            const int m = eb[base + e];
            const float4 v = fb4[(m << 6) + lane];
            acc += fmaf(px, v.x, fmaf(py, v.y, fmaf(pz, v.z, v.w)));
        }
        T[jj][lane] = acc;
    }
    __syncthreads();

    float* outb = out + (size_t)b * COUT_ * N_;
    for (int r = 0; r < 16; ++r) {
        const int o = r * 4 + w;
        outb[(size_t)o * N_ + n0 + lane] = T[lane][o] + bias[o];
    }
}

// ===========================================================================
// PATH C (16 MiB ws): verified atomic-scatter fallback.
// ===========================================================================
__global__ __launch_bounds__(256) void flexconv_main(
    const float* __restrict__ feat,
    const float* __restrict__ theta,
    const float* __restrict__ wbias,
    const int*   __restrict__ nbh,
    const float* __restrict__ pos,
    float*       __restrict__ ws)
{
    __shared__ float4 Wl[CIN_ * COUT_];
    __shared__ float  Fl[CIN_ * 64];

    const int tid  = threadIdx.x;
    const int lane = tid & 63;
    const int w    = tid >> 6;

    const int blocks_per_b = N_ / 128;
    const int b     = blockIdx.x / blocks_per_b;
    const int nbase = (blockIdx.x % blocks_per_b) * 128;

    for (int e = tid; e < CIN_ * COUT_; e += 256) {
        const int i = e >> 6, o = e & 63;
        float4 wv;
        wv.x = theta[0 * CIN_ * COUT_ + i * COUT_ + o];
        wv.y = theta[1 * CIN_ * COUT_ + i * COUT_ + o];
        wv.z = theta[2 * CIN_ * COUT_ + i * COUT_ + o];
        wv.w = wbias[i * COUT_ + o];
        Wl[e] = wv;
    }

    const float* featb = feat + (size_t)b * CIN_ * N_;
    const float* posb  = pos  + (size_t)b * 3 * N_;
    const int*   nbhb  = nbh  + (size_t)b * K_ * N_;
    float*       wsb   = ws   + (size_t)b * N_ * COUT_;

    for (int t = 0; t < 2; ++t) {
        const int n0 = nbase + t * 64;

        __syncthreads();
        for (int r = 0; r < 16; ++r) {
            const int i = r * 4 + w;
            Fl[i * 64 + lane] = featb[(size_t)i * N_ + n0 + lane];
        }
        __syncthreads();

        for (int g = 0; g < 4; ++g) {
            const int nn = w * 16 + g * 4;
            float4 acc[4];
            #pragma unroll
            for (int j = 0; j < 4; ++j) acc[j] = make_float4(0.f, 0.f, 0.f, 0.f);

            #pragma unroll 8
            for (int i = 0; i < CIN_; ++i) {
                const float4 wv = Wl[i * 64 + lane];
                const float f0 = Fl[i * 64 + nn + 0];
                const float f1 = Fl[i * 64 + nn + 1];
                const float f2 = Fl[i * 64 + nn + 2];
                const float f3 = Fl[i * 64 + nn + 3];
                acc[0].x = fmaf(wv.x, f0, acc[0].x);
                acc[0].y = fmaf(wv.y, f0, acc[0].y);
                acc[0].z = fmaf(wv.z, f0, acc[0].z);
                acc[0].w = fmaf(wv.w, f0, acc[0].w);
                acc[1].x = fmaf(wv.x, f1, acc[1].x);
                acc[1].y = fmaf(wv.y, f1, acc[1].y);
                acc[1].z = fmaf(wv.z, f1, acc[1].z);
                acc[1].w = fmaf(wv.w, f1, acc[1].w);
                acc[2].x = fmaf(wv.x, f2, acc[2].x);
                acc[2].y = fmaf(wv.y, f2, acc[2].y);
                acc[2].z = fmaf(wv.z, f2, acc[2].z);
                acc[2].w = fmaf(wv.w, f2, acc[2].w);
                acc[3].x = fmaf(wv.x, f3, acc[3].x);
                acc[3].y = fmaf(wv.y, f3, acc[3].y);
                acc[3].z = fmaf(wv.z, f3, acc[3].z);
                acc[3].w = fmaf(wv.w, f3, acc[3].w);
            }

            #pragma unroll
            for (int j = 0; j < 4; ++j) {
                const int n = n0 + nn + j;
                const float px = posb[0 * N_ + n];
                const float py = posb[1 * N_ + n];
                const float pz = posb[2 * N_ + n];
                const float4 a = acc[j];
                #pragma unroll
                for (int k = 0; k < K_; ++k) {
                    const int idx = nbhb[k * N_ + n];
                    const float dx = posb[0 * N_ + idx] - px;
                    const float dy = posb[1 * N_ + idx] - py;
                    const float dz = posb[2 * N_ + idx] - pz;
                    const float c  = fmaf(dx, a.x, fmaf(dy, a.y, fmaf(dz, a.z, a.w)));
                    atomicAdd(&wsb[(size_t)idx * COUT_ + lane], c);
                }
            }
        }
    }
}

__global__ __launch_bounds__(256) void flexconv_finish(
    const float* __restrict__ ws,
    const float* __restrict__ bias,
    float*       __restrict__ out)
{
    __shared__ float T[64][65];
    const int tid  = threadIdx.x;
    const int lane = tid & 63;
    const int w    = tid >> 6;

    const int tiles_per_b = N_ / 64;
    const int b  = blockIdx.x / tiles_per_b;
    const int n0 = (blockIdx.x % tiles_per_b) * 64;

    const float* wsb = ws + (size_t)b * N_ * COUT_;
    for (int r = 0; r < 16; ++r) {
        const int nn = r * 4 + w;
        T[nn][lane] = wsb[(size_t)(n0 + nn) * COUT_ + lane];
    }
    __syncthreads();

    float* outb = out + (size_t)b * COUT_ * N_;
    for (int r = 0; r < 16; ++r) {
        const int o = r * 4 + w;
        outb[(size_t)o * N_ + n0 + lane] = T[lane][o] + bias[o];
    }
}

// ===========================================================================
extern "C" void kernel_launch(void* const* d_in, const int* in_sizes, int n_in,
                              void* d_out, int out_size, void* d_ws, size_t ws_size,
                              hipStream_t stream) {
    const float* features = (const float*)d_in[0];
    const float* theta    = (const float*)d_in[1];
    const float* wbias    = (const float*)d_in[2];
    const int*   nbh      = (const int*)  d_in[3];
    const float* pos      = (const float*)d_in[4];
    const float* bias     = (const float*)d_in[5];
    float* out = (float*)d_out;

    const size_t counts_bytes = (size_t)B_ * N_ * sizeof(int);              // 256 KiB
    const size_t map_bytes    = (size_t)TOT_EDGES * sizeof(int);            // 2 MiB

    // ---- Path A layout: contrib + counters + slotmap (~131 MiB) ----
    {
        size_t off = 0;
        float* contrib = (float*)((char*)d_ws + off);
        off += (size_t)TOT_EDGES * COUT_ * sizeof(float);                   // 128 MiB
        int* counts  = (int*)((char*)d_ws + off); off += counts_bytes;
        int* offsets = (int*)((char*)d_ws + off); off += counts_bytes;
        int* cursor  = (int*)((char*)d_ws + off); off += counts_bytes;
        int* slotmap = (int*)((char*)d_ws + off); off += map_bytes;

        if (ws_size >= off) {
            hipMemsetAsync(counts, 0, counts_bytes, stream);
            fc_hist<<<TOT_EDGES / 256, 256, 0, stream>>>(nbh, counts);
            fc_scan<<<B_, 256, 0, stream>>>(counts, offsets, cursor);
            fc_fill_slot<<<TOT_EDGES / 256, 256, 0, stream>>>(nbh, cursor, slotmap);
            fc_contrib<<<B_ * (N_ / 128), 256, 0, stream>>>(features, theta, wbias,
                                                            nbh, slotmap, pos, contrib);
            fc_gather3<<<B_ * (N_ / 64), 512, 0, stream>>>(contrib, offsets, counts,
                                                           bias, out);
            return;
        }
    }

    // ---- Path B layout: ftfb + counters + edges (~67 MiB) ----
    {
        size_t off = 0;
        float4* ftfb = (float4*)((char*)d_ws + off);
        off += (size_t)B_ * N_ * COUT_ * sizeof(float4);                    // 64 MiB
        int* counts  = (int*)((char*)d_ws + off); off += counts_bytes;
        int* offsets = (int*)((char*)d_ws + off); off += counts_bytes;
        int* cursor  = (int*)((char*)d_ws + off); off += counts_bytes;
        int* edges   = (int*)((char*)d_ws + off); off += map_bytes;

        if (ws_size >= off) {
            hipMemsetAsync(counts, 0, counts_bytes, stream);
            fc_hist<<<TOT_EDGES / 256, 256, 0, stream>>>(nbh, counts);
            fc_scan<<<B_, 256, 0, stream>>>(counts, offsets, cursor);
            fc_fill<<<TOT_EDGES / 256, 256, 0, stream>>>(nbh, cursor, edges);
            fc_ftfb<<<B_ * (N_ / 128), 256, 0, stream>>>(features, theta, wbias, pos, ftfb);
            fc_gather<<<B_ * (N_ / 64), 256, 0, stream>>>(ftfb, edges, offsets, counts,
                                                          pos, bias, out);
            return;
        }
    }

    // ---- Path C: atomic fallback (16 MiB) ----
    {
        float* ws = (float*)d_ws;
        const size_t ws_bytes = (size_t)B_ * N_ * COUT_ * sizeof(float);
        hipMemsetAsync(ws, 0, ws_bytes, stream);
        flexconv_main<<<B_ * (N_ / 128), 256, 0, stream>>>(features, theta, wbias,
                                                           nbh, pos, ws);
        flexconv_finish<<<B_ * (N_ / 64), 256, 0, stream>>>(ws, bias, out);
    }
}